// Round 7
// baseline (238.078 us; speedup 1.0000x reference)
//
#include <hip/hip_runtime.h>

// Problem constants (HyperNetwork_9990093931021)
#define BB 256   // batch
#define CC 512   // channels
#define NZ 256   // flattened spatial (16*16)
#define ZD 64    // z_dim
#define KK 9     // out_c * f * f = 1*3*3
#define CT 8     // channels per out-tile
#define NCT (CC / CT)        // 64 ctiles
#define WFT (KK * CT * 32)   // floats per (ctile,k? no): KK*8*32 = 2304 per k-slice? see layout
// wf tile per ctile = KK * 8(j) * 256(lane*4) = 18432 floats = 73728 B

// ---- DPP cross-lane add helpers (VALU-only, no LDS pipe) ----
template<int CTRL>
__device__ __forceinline__ float dpp_add(float v) {
    int o = __builtin_amdgcn_update_dpp(0, __float_as_int(v), CTRL, 0xF, 0xF, true);
    return v + __int_as_float(o);
}
// sum over aligned 8-lane group
__device__ __forceinline__ float red8(float v) {
    v = dpp_add<0xB1>(v);   // quad_perm [1,0,3,2]  (xor 1)
    v = dpp_add<0x4E>(v);   // quad_perm [2,3,0,1]  (xor 2)
    v = dpp_add<0x141>(v);  // row_half_mirror      (combine quads of 8-lane half)
    return v;
}

// async global->LDS: one wave call stages 1024 B (lane i -> ldsbase + 16*i).
// Global source is PER-LANE (pre-swizzle allowed); LDS dest is linear.
typedef __attribute__((address_space(1))) const void gconst_t;
typedef __attribute__((address_space(3))) void lds_t;
__device__ __forceinline__ void load_1k_to_lds(const float* gp, float* lp) {
    __builtin_amdgcn_global_load_lds((gconst_t*)gp, (lds_t*)lp, 16, 0, 0);
}

// ============================================================================
// Kernel A: build fused weight and bias.
//   Wf[c][k][n] = sum_z W_in[c,n,z] * W_out[z,k]
//   bk[c][k]    = b_in[c,:].W_out[:,k] + b_out[k]
// NEW LAYOUT for wf (so out_kernel reads are contiguous):
//   wf[ ((ct*KK + k)*8 + j)*8*32 + cc*32 + nn ]  with c = ct*8+cc, n = j*32+nn
// grid = C blocks x 512 threads. Reads W_in once (33.5 MB). ~8 µs.
// ============================================================================
__global__ __launch_bounds__(512, 2)
void wf_kernel(const float* __restrict__ W_in,
               const float* __restrict__ b_in,
               const float* __restrict__ W_out,
               const float* __restrict__ b_out,
               float* __restrict__ wf,    // [NCT][KK][8][8][32] transposed layout
               float* __restrict__ bk) {  // [C][KK]
    __shared__ __align__(16) float s_woutT[KK * ZD]; // W_out transposed, [k][z]
    __shared__ float s_bin[ZD];

    const int c = blockIdx.x;
    const int t = threadIdx.x;
    const int ct = c >> 3, cc = c & 7;

    for (int i = t; i < KK * ZD; i += 512) {
        float v = W_out[i];
        int zz = i / KK, k = i - zz * KK;
        s_woutT[k * ZD + zz] = v;
    }
    if (t < ZD) s_bin[t] = b_in[c * ZD + t];
    __syncthreads();

    const int n = t >> 1, half = t & 1;            // 2 threads per n, 32 z each
    const float* wrow = W_in + ((size_t)c * NZ + n) * ZD + half * 32;
    float acc[KK];
#pragma unroll
    for (int k = 0; k < KK; ++k) acc[k] = 0.f;
#pragma unroll
    for (int j = 0; j < 8; ++j) {
        const float4 w = *reinterpret_cast<const float4*>(wrow + 4 * j);
#pragma unroll
        for (int k = 0; k < KK; ++k) {
            const float4 wo = *reinterpret_cast<const float4*>(
                &s_woutT[k * ZD + half * 32 + 4 * j]);
            acc[k] += w.x * wo.x + w.y * wo.y + w.z * wo.z + w.w * wo.w;
        }
    }
#pragma unroll
    for (int k = 0; k < KK; ++k) acc[k] = dpp_add<0xB1>(acc[k]); // half0+half1
    if (half == 0) {
        const int j = n >> 5, nn = n & 31;
#pragma unroll
        for (int k = 0; k < KK; ++k)
            wf[(((size_t)ct * KK + k) * 8 + j) * 256 + cc * 32 + nn] = acc[k];
    }
    if (t < KK) { // fused bias
        float s = 0.f;
        for (int zz = 0; zz < ZD; ++zz) s += s_bin[zz] * s_woutT[t * ZD + zz];
        bk[c * KK + t] = s + b_out[t];
    }
}

// ============================================================================
// Kernel B v5: out[b,c,k] = z[b,c,:].Wf[c][k][:] + bk[c][k]
//
// vs v1-v4 (all ~2.1 TB/s): those walked one channel COLUMN per block —
// 1 KB rows at exactly 512 KB (2^19) stride -> DRAM channel/bank bits
// constant -> bank-camping, row-activate bound. v5 tiles over CHANNELS:
// per wave-step the wave consumes z[b][c0:c0+8][:] = one CONTIGUOUS 8 KB
// span; consecutive steps advance b. Sequential pages, all banks hit.
//
// grid = (NCT=64, BB/16=16) x 256 threads (4 waves). Block: 8 channels x
// 16 b. Wave w owns b = bt*16 + s*4 + w, s=0..3. Wave-private double-
// buffered 8 KB slabs, counted vmcnt(8) self-pacing (v4 template, proven).
// z staged with pre-swizzled per-lane global addrs so LDS = [j][lane]:
// compute reads of z AND wf are fully contiguous 1 KB wave-reads.
// LDS = 73.7 KB wf + 64 KB z + 0.3 = 138 KB -> 1 block/CU (4 waves, each
// with 16 KB in flight -> 64 KB/CU: enough by Little's law for 6 TB/s).
// Reduction op-order identical to verified v1/v3/v4.
// ============================================================================
__global__ __launch_bounds__(256, 1)
void out_kernel(const float* __restrict__ z,
                const float* __restrict__ wf,   // [NCT][KK][8][256] floats
                const float* __restrict__ bk,   // [C][KK]
                float* __restrict__ out) {
    __shared__ __align__(16) float s_wf[KK * 8 * 256];   // 73728 B, [k][j][l*4]
    __shared__ float s_biask[CT][KK];                    // [cc][k]
    __shared__ __align__(16) float s_z[4][2][8 * 256];   // [wave][buf][8 KB]

    const int ct = blockIdx.x;          // channel tile (8 channels)
    const int bt = blockIdx.y;          // batch tile (16 b)
    const int c0 = ct * CT;
    const int t = threadIdx.x;
    const int lane = t & 63;
    const int wave = t >> 6;            // 0..3
    const int g = lane >> 3;            // 8-lane group = one channel cc
    const int sub = lane & 7;           // slice of the n dimension

    // ---- stage wf tile: 73728 B CONTIGUOUS, 72 x 1 KB async calls ----
    {
        const float* src = wf + (size_t)ct * (KK * 8 * 256);
        for (int q = wave * 18; q < wave * 18 + 18; ++q)
            load_1k_to_lds(src + q * 256 + lane * 4, &s_wf[q * 256]);
    }
    if (t < CT * KK) s_biask[t / KK][t % KK] = bk[(c0 + t / KK) * KK + t % KK];
    __syncthreads();   // drains vmcnt+lgkm: wf/bias visible; z-ledger clean

    const float biasS = s_biask[g][sub];
    const float bias8 = s_biask[g][8];

    // wave's batch stream: b = bq + s*4, s = 0..3
    const int bq = bt * 16 + wave;
    const float* zb0 = z + ((size_t)bq * CC + c0) * NZ;  // step-0 base (8 KB span)
    const size_t sstr = (size_t)4 * CC * NZ;             // per-step stride (floats)
    // per-lane swizzled source offset: lane i reads z[.][c0+(i>>3)][q*32+(i&7)*4]
    const size_t lsw = (size_t)(lane >> 3) * NZ + (lane & 7) * 4;

    float* const slab0 = s_z[wave][0];
    float* const slab1 = s_z[wave][1];

    // ---- issue slabs for steps 0 and 1 (8 x 1 KB calls each) ----
#pragma unroll
    for (int q = 0; q < 8; ++q)
        load_1k_to_lds(zb0 + lsw + q * 32, &slab0[q * 256]);
#pragma unroll
    for (int q = 0; q < 8; ++q)
        load_1k_to_lds(zb0 + sstr + lsw + q * 32, &slab1[q * 256]);

    float vsel[4], v8[4];   // deferred outputs (static-indexed: loop unrolled)

#pragma unroll
    for (int s = 0; s < 4; ++s) {
        float* const slab = (s & 1) ? slab1 : slab0;

        // ledger holds only this wave's z loads: wait oldest slab landed
        if (s < 3) asm volatile("s_waitcnt vmcnt(8)" ::: "memory");
        else       asm volatile("s_waitcnt vmcnt(0)" ::: "memory");
        __builtin_amdgcn_sched_barrier(0);

        // ---- compute: group g = channel c0+g, this wave's b ----
        float acc[KK];
#pragma unroll
        for (int k = 0; k < KK; ++k) acc[k] = 0.f;
#pragma unroll
        for (int j = 0; j < 8; ++j) {
            const float4 x = *reinterpret_cast<const float4*>(
                &slab[j * 256 + lane * 4]);            // contiguous 1 KB wave-read
#pragma unroll
            for (int k = 0; k < KK; ++k) {
                const float4 w = *reinterpret_cast<const float4*>(
                    &s_wf[(k * 8 + j) * 256 + lane * 4]);  // contiguous 1 KB
                acc[k] += x.x * w.x + x.y * w.y + x.z * w.z + x.w * w.w;
            }
        }
#pragma unroll
        for (int k = 0; k < KK; ++k) acc[k] = red8(acc[k]);  // sum over sub

        float v = acc[0];
#pragma unroll
        for (int k = 1; k < 8; ++k) {
            if (sub == k) v = acc[k];   // cndmask chain
        }
        vsel[s] = v;
        v8[s] = acc[8];

        // ---- re-issue into just-computed buffer (step s+2) ----
        if (s < 2) {
            asm volatile("s_waitcnt lgkmcnt(0)" ::: "memory");  // ds_reads retired
            __builtin_amdgcn_sched_barrier(0);
            const float* zn = zb0 + (size_t)(s + 2) * sstr;
#pragma unroll
            for (int q = 0; q < 8; ++q)
                load_1k_to_lds(zn + lsw + q * 32, &slab[q * 256]);
        }
    }

    // ---- epilogue: stores (outside the vmcnt ledger) ----
#pragma unroll
    for (int s = 0; s < 4; ++s) {
        const int b = bq + s * 4;
        const size_t o0 = ((size_t)b * CC + c0 + g) * KK;
        out[o0 + sub] = vsel[s] + biasS;
        if (sub == 0) out[o0 + 8] = v8[s] + bias8;
    }
}

// ============================================================================
// Fallback: previous session's fused single kernel (harness-verified),
// used only if the workspace is too small for the split path.
// ============================================================================
__global__ __launch_bounds__(512, 2)
void hyper_kernel(const float* __restrict__ z,
                  const float* __restrict__ W_in,
                  const float* __restrict__ b_in,
                  const float* __restrict__ W_out,
                  const float* __restrict__ b_out,
                  float* __restrict__ out) {
    __shared__ __align__(16) float s_wfT[KK * NZ];   // fused weight, [k][n]
    __shared__ __align__(16) float s_woutT[KK * ZD]; // W_out transposed, [k][z]
    __shared__ float s_bin[ZD];
    __shared__ float s_biask[KK];

    const int c = blockIdx.x;
    const int t = threadIdx.x;

    for (int i = t; i < KK * ZD; i += 512) {
        float v = W_out[i];
        int zz = i / KK, k = i - zz * KK;
        s_woutT[k * ZD + zz] = v;
    }
    if (t < ZD) s_bin[t] = b_in[c * ZD + t];
    __syncthreads();

    {
        const int n = t >> 1, half = t & 1;
        const float* wrow = W_in + ((size_t)c * NZ + n) * ZD + half * 32;
        float acc[KK];
#pragma unroll
        for (int k = 0; k < KK; ++k) acc[k] = 0.f;
#pragma unroll
        for (int j = 0; j < 8; ++j) {
            const float4 w = *reinterpret_cast<const float4*>(wrow + 4 * j);
#pragma unroll
            for (int k = 0; k < KK; ++k) {
                const float4 wo = *reinterpret_cast<const float4*>(
                    &s_woutT[k * ZD + half * 32 + 4 * j]);
                acc[k] += w.x * wo.x + w.y * wo.y + w.z * wo.z + w.w * wo.w;
            }
        }
#pragma unroll
        for (int k = 0; k < KK; ++k) acc[k] = dpp_add<0xB1>(acc[k]);
        if (half == 0) {
#pragma unroll
            for (int k = 0; k < KK; ++k) s_wfT[k * NZ + n] = acc[k];
        }
        if (t < KK) {
            float s = 0.f;
            for (int zz = 0; zz < ZD; ++zz) s += s_bin[zz] * s_woutT[t * ZD + zz];
            s_biask[t] = s + b_out[t];
        }
    }
    __syncthreads();

    const int lane = t & 63;
    const int wave = t >> 6;
    const int g = lane >> 3;
    const int sub = lane & 7;
    const int b0 = wave * 32 + g * 4;
    const float biasS = s_biask[sub];
    const float bias8 = s_biask[8];

    const float* xp = z + ((size_t)b0 * CC + c) * NZ + sub * 4;
    const size_t bstr = (size_t)CC * NZ;

    float acc[4][KK];
#pragma unroll
    for (int bb = 0; bb < 4; ++bb)
#pragma unroll
        for (int k = 0; k < KK; ++k) acc[bb][k] = 0.f;

    float4 xb[2][4];
#pragma unroll
    for (int bb = 0; bb < 4; ++bb)
        xb[0][bb] = *reinterpret_cast<const float4*>(xp + bb * bstr);

#pragma unroll
    for (int j = 0; j < 8; ++j) {
        if (j < 7) {
#pragma unroll
            for (int bb = 0; bb < 4; ++bb)
                xb[(j + 1) & 1][bb] =
                    *reinterpret_cast<const float4*>(xp + bb * bstr + (j + 1) * 32);
        }
#pragma unroll
        for (int k = 0; k < KK; ++k) {
            const float4 wfv = *reinterpret_cast<const float4*>(
                &s_wfT[k * NZ + sub * 4 + j * 32]);
#pragma unroll
            for (int bb = 0; bb < 4; ++bb) {
                const float4 x = xb[j & 1][bb];
                acc[bb][k] += x.x * wfv.x + x.y * wfv.y + x.z * wfv.z + x.w * wfv.w;
            }
        }
    }

#pragma unroll
    for (int bb = 0; bb < 4; ++bb)
#pragma unroll
        for (int k = 0; k < KK; ++k) acc[bb][k] = red8(acc[bb][k]);

#pragma unroll
    for (int bb = 0; bb < 4; ++bb) {
        float v = acc[bb][0];
#pragma unroll
        for (int k = 1; k < 8; ++k) {
            if (sub == k) v = acc[bb][k];
        }
        const size_t o0 = ((size_t)(b0 + bb) * CC + c) * KK;
        out[o0 + sub] = v + biasS;
        if (sub == 0) out[o0 + 8] = acc[bb][8] + bias8;
    }
}

extern "C" void kernel_launch(void* const* d_in, const int* in_sizes, int n_in,
                              void* d_out, int out_size, void* d_ws, size_t ws_size,
                              hipStream_t stream) {
    const float* z     = (const float*)d_in[0];
    const float* W_in  = (const float*)d_in[1];
    const float* b_in  = (const float*)d_in[2];
    const float* W_out = (const float*)d_in[3];
    const float* b_out = (const float*)d_in[4];
    float* out = (float*)d_out;

    const size_t WF_ELTS = (size_t)NCT * KK * 8 * 256; // 1,179,648 floats (4.72 MB)
    const size_t BK_ELTS = (size_t)CC * KK;            // 4,608 floats
    const size_t NEED = (WF_ELTS + BK_ELTS) * sizeof(float);

    if (d_ws != nullptr && ws_size >= NEED) {
        float* wfp = (float*)d_ws;
        float* bkp = wfp + WF_ELTS;
        wf_kernel<<<dim3(CC), dim3(512), 0, stream>>>(W_in, b_in, W_out, b_out, wfp, bkp);
        out_kernel<<<dim3(NCT, BB / 16), dim3(256), 0, stream>>>(z, wfp, bkp, out);
    } else {
        hyper_kernel<<<dim3(CC), dim3(512), 0, stream>>>(z, W_in, b_in, W_out, b_out, out);
    }
}